// Round 5
// baseline (198.123 us; speedup 1.0000x reference)
//
#include <hip/hip_runtime.h>
#include <hip/hip_fp16.h>

// TopologyNetwork: B=1024, N=5000, K=16, 9 levels.
// R5: gather moved from L2 (random ~9 TB/s) into LDS (~69 TB/s).
// Activations stored [G=256 groups][N][C=4 cols] f16 (8 B per node-row).
// Per level, block g streams its 40 KB slice into LDS, then each lane
// (=node) gathers predecessor rows from LDS via ds_read_b64. Edge data
// pre-packed per call into [L][K][N] u32 = (u16 idx | f16(w)<<16) so the
// inner edge load is a coalesced 4 B/lane read of an L2-resident array.
// g -> XCD via grid=256 round-robin keeps act slices L2-resident.

#define TB 1024
#define TN 5000
#define TK 16
#define TLV 9
#define CPG 4                 // batch columns per group
#define NG  (TB / CPG)        // 256 groups = grid size
#define LT  1024              // threads per level-block

typedef unsigned int u32;
typedef unsigned short u16;

__device__ __forceinline__ u32 pack2h(float a, float b) {
    u32 lo = (u32)__half_as_ushort(__float2half(a));
    u32 hi = (u32)__half_as_ushort(__float2half(b));
    return lo | (hi << 16);
}
__device__ __forceinline__ float h_lo(u32 v) {
    return __half2float(__ushort_as_half((u16)(v & 0xffffu)));
}
__device__ __forceinline__ float h_hi(u32 v) {
    return __half2float(__ushort_as_half((u16)(v >> 16)));
}

// ---- pack edges: idx i32 [L][N][K] + w f32 [L][N][K] -> pe u32 [L][K][N] ----
__global__ __launch_bounds__(256) void k_pack_edges(
    const int* __restrict__ idx, const float* __restrict__ w,
    u32* __restrict__ pe)
{
    const int l  = blockIdx.y;
    const int n0 = blockIdx.x * 256;
    const int t  = threadIdx.x;
    __shared__ u32 tile[256 * 17];            // [n_local][k], pad 17 vs bank conflicts
    const size_t base = ((size_t)l * TN + n0) * TK;
    const int nloc = min(256, TN - n0);
    for (int j = t; j < nloc * TK; j += 256) {       // coalesced reads
        int   nl = j / TK, k = j % TK;
        int   v  = idx[base + j];
        float wf = w[base + j];
        tile[nl * 17 + k] = (u32)(v & 0xffff) |
                            ((u32)__half_as_ushort(__float2half(wf)) << 16);
    }
    __syncthreads();
    for (int j = t; j < TK * 256; j += 256) {        // coalesced writes over n
        int k = j >> 8, r = j & 255;
        u32 v = tile[r * 17 + k];
        if (n0 + r < TN) pe[((size_t)l * TK + k) * TN + n0 + r] = v;
    }
}

// ---- transpose-in: x f32 [B,N] -> act f16 [G][N][C] (as u32 pairs) ----
__global__ __launch_bounds__(256) void k_tin(
    const float* __restrict__ x, u32* __restrict__ act)
{
    const int g = blockIdx.x;
    const int t = threadIdx.x;
    const float* r0 = x + (size_t)(g * CPG + 0) * TN;
    const float* r1 = x + (size_t)(g * CPG + 1) * TN;
    const float* r2 = x + (size_t)(g * CPG + 2) * TN;
    const float* r3 = x + (size_t)(g * CPG + 3) * TN;
    u32* dst = act + (size_t)g * TN * 2;
    for (int n = t; n < TN; n += 256) {
        uint2 v;
        v.x = pack2h(r0[n], r1[n]);
        v.y = pack2h(r2[n], r3[n]);
        *reinterpret_cast<uint2*>(&dst[n * 2]) = v;
    }
}

// ---- one DAG level: LDS-gather ----
__global__ __launch_bounds__(LT) void k_level(
    const u32* __restrict__ in,     // act prev [NG][TN][2]
    u32* __restrict__ outa,         // act next [NG][TN][2]
    const u32* __restrict__ pe,     // [TK][TN] packed edges this level
    const float* __restrict__ bias) // [TN] this level
{
    __shared__ u32 lds[TN * 2];     // 40 KB: this group's prev-level slice
    const int g = blockIdx.x;
    const int t = threadIdx.x;

    // stage: contiguous 40 KB, coalesced b64
    const u32* src = in + (size_t)g * TN * 2;
    for (int j = t; j < TN; j += LT) {
        *reinterpret_cast<uint2*>(&lds[j * 2]) =
            *reinterpret_cast<const uint2*>(&src[j * 2]);
    }
    __syncthreads();

    u32* dst = outa + (size_t)g * TN * 2;
    for (int n = t; n < TN; n += LT) {
        const float bv = bias[n];
        float a0 = bv, a1 = bv, a2 = bv, a3 = bv;
        #pragma unroll
        for (int k = 0; k < TK; ++k) {
            const u32 e = pe[(size_t)k * TN + n];   // coalesced, L2-resident
            const u32 s = e & 0xffffu;
            const float wv = __half2float(__ushort_as_half((u16)(e >> 16)));
            const uint2 av = *reinterpret_cast<const uint2*>(&lds[s * 2]); // ds_read_b64
            a0 = fmaf(wv, h_lo(av.x), a0);
            a1 = fmaf(wv, h_hi(av.x), a1);
            a2 = fmaf(wv, h_lo(av.y), a2);
            a3 = fmaf(wv, h_hi(av.y), a3);
        }
        a0 = a0 > 0.0f ? a0 : 0.1f * a0;
        a1 = a1 > 0.0f ? a1 : 0.1f * a1;
        a2 = a2 > 0.0f ? a2 : 0.1f * a2;
        a3 = a3 > 0.0f ? a3 : 0.1f * a3;
        uint2 r;
        r.x = pack2h(a0, a1);
        r.y = pack2h(a2, a3);
        *reinterpret_cast<uint2*>(&dst[n * 2]) = r;
    }
}

// ---- transpose-out: act f16 [G][N][C] -> out f32 [B,N] ----
__global__ __launch_bounds__(256) void k_tout(
    const u32* __restrict__ act, float* __restrict__ out)
{
    const int g = blockIdx.x;
    const int t = threadIdx.x;
    const u32* src = act + (size_t)g * TN * 2;
    float* r0 = out + (size_t)(g * CPG + 0) * TN;
    float* r1 = out + (size_t)(g * CPG + 1) * TN;
    float* r2 = out + (size_t)(g * CPG + 2) * TN;
    float* r3 = out + (size_t)(g * CPG + 3) * TN;
    for (int n = t; n < TN; n += 256) {
        const uint2 v = *reinterpret_cast<const uint2*>(&src[n * 2]);
        r0[n] = h_lo(v.x);
        r1[n] = h_hi(v.x);
        r2[n] = h_lo(v.y);
        r3[n] = h_hi(v.y);
    }
}

extern "C" void kernel_launch(void* const* d_in, const int* in_sizes, int n_in,
                              void* d_out, int out_size, void* d_ws, size_t ws_size,
                              hipStream_t stream)
{
    const float* x       = (const float*)d_in[0];   // [B,N]
    const int*   src_idx = (const int*)  d_in[1];   // [LV,N,K]
    const float* weights = (const float*)d_in[2];   // [LV,N,K]
    const float* biases  = (const float*)d_in[3];   // [LV,N]
    float* out = (float*)d_out;                     // [B,N]

    u32* actA = (u32*)d_ws;                         // [NG][TN][2] = 10.24 MB
    u32* actB = actA + (size_t)NG * TN * 2;         // 10.24 MB
    u32* pe   = actB + (size_t)NG * TN * 2;         // [LV][TK][TN] = 2.88 MB

    // pack edges (every call; deterministic)
    {
        dim3 grid((TN + 255) / 256, TLV);
        hipLaunchKernelGGL(k_pack_edges, grid, dim3(256), 0, stream,
                           src_idx, weights, pe);
    }
    // x -> actA
    hipLaunchKernelGGL(k_tin, dim3(NG), dim3(256), 0, stream, x, actA);

    u32* cur = actA;
    u32* nxt = actB;
    for (int l = 0; l < TLV; ++l) {
        hipLaunchKernelGGL(k_level, dim3(NG), dim3(LT), 0, stream,
                           cur, nxt,
                           pe + (size_t)l * TK * TN,
                           biases + (size_t)l * TN);
        u32* tmp = cur; cur = nxt; nxt = tmp;
    }

    hipLaunchKernelGGL(k_tout, dim3(NG), dim3(256), 0, stream, cur, out);
}